// Round 16
// baseline (431.604 us; speedup 1.0000x reference)
//
#include <hip/hip_runtime.h>
#include <hip/hip_bf16.h>

#define BB 64
#define TT 512
#define FF 1024
#define KK 64

typedef unsigned char uchar;

// ---------------- Emission GEMM (round-1 version, measured ~83-88us, 6x) ----------------
#define BM 64
#define BF 64
#define LDA 68

__global__ __launch_bounds__(256)
void emission_kernel(const float* __restrict__ X, const float* __restrict__ W,
                     const float* __restrict__ bias, float* __restrict__ em)
{
    __shared__ float As[BF][LDA];
    __shared__ float Bs[BF][LDA];
    const int tid = threadIdx.x;
    const int row0 = blockIdx.x * BM;
    const int tm = tid & 15;
    const int tn = tid >> 4;
    const int lq = tid & 15;
    const int lr = tid >> 4;

    float acc[4][4];
#pragma unroll
    for (int i = 0; i < 4; ++i)
#pragma unroll
        for (int jj = 0; jj < 4; ++jj) acc[i][jj] = 0.f;

    for (int f0 = 0; f0 < FF; f0 += BF) {
#pragma unroll
        for (int p = 0; p < 4; ++p) {
            const int r = p * 16 + lr;
            float4 a = *(const float4*)(X + (size_t)(row0 + r) * FF + f0 + lq * 4);
            As[lq * 4 + 0][r] = a.x;
            As[lq * 4 + 1][r] = a.y;
            As[lq * 4 + 2][r] = a.z;
            As[lq * 4 + 3][r] = a.w;
            float4 w = *(const float4*)(W + (size_t)r * FF + f0 + lq * 4);
            Bs[lq * 4 + 0][r] = w.x;
            Bs[lq * 4 + 1][r] = w.y;
            Bs[lq * 4 + 2][r] = w.z;
            Bs[lq * 4 + 3][r] = w.w;
        }
        __syncthreads();
#pragma unroll
        for (int f = 0; f < BF; ++f) {
            float4 a = *(const float4*)&As[f][tm * 4];
            float4 b = *(const float4*)&Bs[f][tn * 4];
            acc[0][0] += a.x * b.x; acc[0][1] += a.x * b.y; acc[0][2] += a.x * b.z; acc[0][3] += a.x * b.w;
            acc[1][0] += a.y * b.x; acc[1][1] += a.y * b.y; acc[1][2] += a.y * b.z; acc[1][3] += a.y * b.w;
            acc[2][0] += a.z * b.x; acc[2][1] += a.z * b.y; acc[2][2] += a.z * b.z; acc[2][3] += a.z * b.w;
            acc[3][0] += a.w * b.x; acc[3][1] += a.w * b.y; acc[3][2] += a.w * b.z; acc[3][3] += a.w * b.w;
        }
        __syncthreads();
    }

    const float4 b4 = *(const float4*)(bias + tn * 4);
#pragma unroll
    for (int i = 0; i < 4; ++i) {
        float4 o;
        o.x = acc[i][0] + b4.x;
        o.y = acc[i][1] + b4.y;
        o.z = acc[i][2] + b4.z;
        o.w = acc[i][3] + b4.w;
        *(float4*)(em + (size_t)(row0 + tm * 4 + i) * KK + tn * 4) = o;
    }
}

// ---------------- Forward: value-only recurrence, 8 waves/block = 2 waves/SIMD ----------------
// r10-r15 synthesis: a SOLO wave issues at best 1 instr per ~4 cycles (issue
// cadence), regardless of ILP, tc residency, or SGPR hazards. Fix: co-residency.
// 512-thread blocks (8 waves, round-robin over 4 SIMDs) = 2 waves/SIMD -> the
// SIMD alternates waves, ~2 cy/instr effective. To keep VGPR count SMALL (so
// the allocator's high-occupancy heuristic works FOR us), tc lives in LDS:
// transposed, padded [64][68] (272B rows: 16B-aligned b128, bank-floor), and
// DOUBLE-COPIED indexed by t&1 so LICM cannot hoist 64 floats into registers.
#define CHUNKL(B) do {                                                         \
    float r0, r1, r2, r3, r4, r5, r6, r7;                                      \
    asm("v_readlane_b32 %0, %8, %9\n\t"                                        \
        "v_readlane_b32 %1, %8, %10\n\t"                                       \
        "v_readlane_b32 %2, %8, %11\n\t"                                       \
        "v_readlane_b32 %3, %8, %12\n\t"                                       \
        "v_readlane_b32 %4, %8, %13\n\t"                                       \
        "v_readlane_b32 %5, %8, %14\n\t"                                       \
        "v_readlane_b32 %6, %8, %15\n\t"                                       \
        "v_readlane_b32 %7, %8, %16\n\t"                                       \
        : "=s"(r0), "=s"(r1), "=s"(r2), "=s"(r3),                              \
          "=s"(r4), "=s"(r5), "=s"(r6), "=s"(r7)                               \
        : "v"(score),                                                          \
          "i"((B) + 0), "i"((B) + 1), "i"((B) + 2), "i"((B) + 3),              \
          "i"((B) + 4), "i"((B) + 5), "i"((B) + 6), "i"((B) + 7));             \
    const float4 t0 = *(const float4*)(tcp + (B));                             \
    const float4 t1 = *(const float4*)(tcp + (B) + 4);                         \
    const float v0 = r0 + t0.x;                                                \
    const float v1 = r1 + t0.y;                                                \
    const float v2 = r2 + t0.z;                                                \
    const float v3 = r3 + t0.w;                                                \
    const float v4 = r4 + t1.x;                                                \
    const float v5 = r5 + t1.y;                                                \
    const float v6 = r6 + t1.z;                                                \
    const float v7 = r7 + t1.w;                                                \
    const float ma = fmaxf(fmaxf(v0, v1), v2);   /* v_max3 */                  \
    const float mb = fmaxf(fmaxf(v3, v4), v5);                                 \
    const float mc = fmaxf(fmaxf(v6, v7), ma);                                 \
    const float w_ = fmaxf(mb, mc);                                            \
    m_ = ((B) == 0) ? w_ : fmaxf(m_, w_);                                      \
} while (0)

#define VSTEP(EV, TIDX) do {                                                   \
    const float* tcp = &tcT[(TIDX) & 1][j][0];                                 \
    float m_;                                                                  \
    CHUNKL(0);  CHUNKL(8);  CHUNKL(16); CHUNKL(24);                            \
    CHUNKL(32); CHUNKL(40); CHUNKL(48); CHUNKL(56);                            \
    score = m_ + (EV);                                                         \
    sb[(size_t)(TIDX) * KK + j] = score;                                       \
} while (0)

#define RLANE(I) __uint_as_float((unsigned)__builtin_amdgcn_readlane((int)__float_as_uint(score), (I)))

__global__ __launch_bounds__(512)
void viterbi_fwd(const float* __restrict__ em, const void* __restrict__ maskp,
                 const float* __restrict__ startT, const float* __restrict__ endT,
                 const float* __restrict__ trans, float* __restrict__ shist,
                 int* __restrict__ btarr)
{
    __shared__ float tcT[2][KK][68];   // tcT[ph][j][i] = trans[i][j], both copies

    const int tid = threadIdx.x;
    const int wv = tid >> 6;                 // wave 0..7
    const int b = blockIdx.x * 8 + wv;       // sequence id
    const int j = tid & 63;

    // cooperative staging of transposed trans into both LDS copies
#pragma unroll
    for (int p = 0; p < 8; ++p) {
        const int idx = p * 512 + tid;       // 0..4095
        const int i = idx >> 6, jj = idx & 63;
        const float v = trans[idx];
        tcT[0][jj][i] = v;
        tcT[1][jj][i] = v;
    }
    __syncthreads();

    const uchar* m8 = (const uchar*)maskp;
    const int* m32 = (const int*)maskp;
    const bool u8m = (m8[1] != 0);

    // ---- length precompute (mask monotone: true for t < len) ----
    int myc;
    if (u8m) {
        const uint2 mv = *(const uint2*)(m8 + (size_t)b * TT + j * 8);
        const unsigned s4 = (mv.x & 0x01010101u) + (mv.y & 0x01010101u);
        myc = (int)((s4 * 0x01010101u) >> 24);
    } else {
        const int* mp = m32 + (size_t)b * TT + j * 8;
        const int4 a = *(const int4*)mp;
        const int4 c = *(const int4*)(mp + 4);
        myc = (a.x != 0) + (a.y != 0) + (a.z != 0) + (a.w != 0)
            + (c.x != 0) + (c.y != 0) + (c.z != 0) + (c.w != 0);
    }
#pragma unroll
    for (int o = 1; o < 64; o <<= 1) myc += __shfl_xor(myc, o, 64);
    const int len = myc;

    const float* emb = em + (size_t)b * TT * KK;
    float* sb = shist + (size_t)b * TT * KK;

    float score = startT[j] + emb[j];   // t = 0
    sb[j] = score;

    float eA = emb[1 * KK + j];
    float eB = emb[2 * KK + j];
    float eC = emb[3 * KK + j];
    float eD = emb[4 * KK + j];

    int t = 1;
    for (; t + 3 < len; t += 4) {
        VSTEP(eA, t);     eA = emb[(size_t)((t + 4 < TT) ? t + 4 : TT - 1) * KK + j];
        VSTEP(eB, t + 1); eB = emb[(size_t)((t + 5 < TT) ? t + 5 : TT - 1) * KK + j];
        VSTEP(eC, t + 2); eC = emb[(size_t)((t + 6 < TT) ? t + 6 : TT - 1) * KK + j];
        VSTEP(eD, t + 3); eD = emb[(size_t)((t + 7 < TT) ? t + 7 : TT - 1) * KK + j];
    }
    for (; t < len; ++t) {
        VSTEP(eA, t);
        eA = eB; eB = eC; eC = eD;
    }

    score += endT[j];
    float bm = -__builtin_inff();
    int bt = 0;
#pragma unroll
    for (int i = 0; i < KK; ++i) {
        const float si = RLANE(i);
        if (si > bm) { bm = si; bt = i; }
    }
    if (j == 0) btarr[b] = bt;
}

// ---------------- hist recompute: massively parallel (validated r8-r15) ----------------
__global__ __launch_bounds__(256)
void hist_kernel(const float* __restrict__ em, const void* __restrict__ maskp,
                 const float* __restrict__ trans, const float* __restrict__ shist,
                 uchar* __restrict__ histg)
{
    const int tid = threadIdx.x;
    const int bid = blockIdx.x;
    const int b = bid >> 6;
    const int t0 = (bid & 63) * 8;

    __shared__ float tl[64][65];
    __shared__ float srow[8][64];

    const uchar* m8 = (const uchar*)maskp;
    const int* m32 = (const int*)maskp;
    const bool u8m = (m8[1] != 0);

#pragma unroll
    for (int p = 0; p < 16; ++p) {
        const int idx = p * 256 + tid;
        tl[idx >> 6][idx & 63] = trans[idx];
    }
#pragma unroll
    for (int p = 0; p < 2; ++p) {
        const int idx = p * 256 + tid;
        const int r = idx >> 6, i2 = idx & 63;
        const int ts = t0 - 1 + r;
        srow[r][i2] = (ts >= 0) ? shist[((size_t)b * TT + ts) * KK + i2] : 0.f;
    }
    __syncthreads();

    const int j = tid & 63;
    const int tq = tid >> 6;

#pragma unroll
    for (int half = 0; half < 2; ++half) {
        const int toff = tq * 2 + half;
        const int t = t0 + toff;
        if (t == 0) continue;
        const int mt = u8m ? (int)m8[b * TT + t] : m32[b * TT + t];
        uchar hv;
        if (!mt) {
            hv = (uchar)j;
        } else {
            const float e = em[((size_t)b * TT + t) * KK + j];
            const float* sr = &srow[toff][0];
            float bm = -__builtin_inff();
            int bi = 0;
#pragma unroll 16
            for (int i = 0; i < KK; ++i) {
                const float cand = (sr[i] + tl[i][j]) + e;   // reference order
                if (cand > bm) { bm = cand; bi = i; }        // strict >: first index
            }
            hv = (uchar)bi;
        }
        histg[((size_t)b * TT + t) * KK + j] = hv;
    }
}

// ---------------- Backtrack (validated r8-r15) ----------------
__global__ __launch_bounds__(256)
void viterbi_bt(const uchar* __restrict__ histg, const int* __restrict__ btarr,
                float* __restrict__ pred)
{
    const int b = blockIdx.x;
    const int tid = threadIdx.x;
    const int w = tid >> 6;
    const int j = tid & 63;

    __shared__ uchar hist[TT][KK];
    __shared__ uchar hypo[8][64][64];

    const uint4* src = (const uint4*)(histg + (size_t)b * TT * KK);
    uint4* dst = (uint4*)&hist[0][0];
#pragma unroll
    for (int p = 0; p < 8; ++p) dst[p * 256 + tid] = src[p * 256 + tid];
    __syncthreads();

    const int bt = btarr[b];

#pragma unroll
    for (int ss = 0; ss < 2; ++ss) {
        const int s = w * 2 + ss;
        int tag = j;
        if (s == 7) {
            hypo[7][63][j] = (uchar)j;
            for (int t = TT - 1; t >= 7 * 64 + 1; --t) {
                tag = hist[t][tag];
                hypo[7][t - 1 - 7 * 64][j] = (uchar)tag;
            }
        } else {
            for (int t = (s + 1) * 64; t >= s * 64 + 1; --t) {
                tag = hist[t][tag];
                hypo[s][t - 1 - s * 64][j] = (uchar)tag;
            }
        }
    }
    __syncthreads();

    int rows_[8];
    rows_[7] = bt;
#pragma unroll
    for (int s = 6; s >= 0; --s) rows_[s] = hypo[s + 1][0][rows_[s + 1]];

    float* pb = pred + (size_t)b * TT;
#pragma unroll
    for (int ss = 0; ss < 2; ++ss) {
        const int s = w * 2 + ss;
        pb[s * 64 + j] = (float)hypo[s][j][rows_[s]];
    }
}

// ---------------- Fallback monolithic viterbi (round-6, proven) ----------------
__global__ __launch_bounds__(256)
void viterbi_kernel(const float* __restrict__ em, const void* __restrict__ maskp,
                    const float* __restrict__ startT, const float* __restrict__ endT,
                    const float* __restrict__ trans, float* __restrict__ pred)
{
    const int b = blockIdx.x;
    const int tid = threadIdx.x;
    const int w = tid >> 6;
    const int j = tid & 63;

    __shared__ uchar hist[TT][KK];
    __shared__ uchar hypo[8][64][64];
    __shared__ int bt_sh;

    const uchar* m8 = (const uchar*)maskp;
    const int* m32 = (const int*)maskp;
    const bool u8m = (m8[1] != 0);

    if (w == 0) {
        float tc[KK];
#pragma unroll
        for (int i = 0; i < KK; ++i) tc[i] = trans[i * KK + j];

        const float* emb = em + (size_t)b * TT * KK;
        float score = startT[j] + emb[j];
        const float endv = endT[j];

        float e_cur = emb[KK + j];
        int   m_cur = u8m ? (int)m8[b * TT + 1] : m32[b * TT + 1];

        int t = 1;
        for (; t < TT; ++t) {
            const int tn2 = (t + 1 < TT) ? (t + 1) : (TT - 1);
            const float e_next = emb[(size_t)tn2 * KK + j];
            const int   m_next = u8m ? (int)m8[b * TT + tn2] : m32[b * TT + tn2];
            if (!m_cur) break;
            float m = -__builtin_inff();
            int idx = 0;
#pragma unroll
            for (int i = 0; i < KK; ++i) {
                const float si = __uint_as_float(__builtin_amdgcn_readlane(__float_as_uint(score), i));
                const float v = (si + tc[i]) + e_cur;
                if (v > m) { m = v; idx = i; }
            }
            score = m;
            hist[t][j] = (uchar)idx;
            e_cur = e_next; m_cur = m_next;
        }
        for (; t < TT; ++t) hist[t][j] = (uchar)j;

        score += endv;
        float bm = -__builtin_inff();
        int bt = 0;
#pragma unroll
        for (int i = 0; i < KK; ++i) {
            const float si = __uint_as_float(__builtin_amdgcn_readlane(__float_as_uint(score), i));
            if (si > bm) { bm = si; bt = i; }
        }
        if (j == 0) bt_sh = bt;
    }
    __syncthreads();

#pragma unroll
    for (int ss = 0; ss < 2; ++ss) {
        const int s = w * 2 + ss;
        int tag = j;
        if (s == 7) {
            hypo[7][63][j] = (uchar)j;
            for (int t = TT - 1; t >= 7 * 64 + 1; --t) {
                tag = hist[t][tag];
                hypo[7][t - 1 - 7 * 64][j] = (uchar)tag;
            }
        } else {
            for (int t = (s + 1) * 64; t >= s * 64 + 1; --t) {
                tag = hist[t][tag];
                hypo[s][t - 1 - s * 64][j] = (uchar)tag;
            }
        }
    }
    __syncthreads();

    const int bt = bt_sh;
    int rows_[8];
    rows_[7] = bt;
#pragma unroll
    for (int s = 6; s >= 0; --s) rows_[s] = hypo[s + 1][0][rows_[s + 1]];

    float* pb = pred + (size_t)b * TT;
#pragma unroll
    for (int ss = 0; ss < 2; ++ss) {
        const int s = w * 2 + ss;
        pb[s * 64 + j] = (float)hypo[s][j][rows_[s]];
    }
}

extern "C" void kernel_launch(void* const* d_in, const int* in_sizes, int n_in,
                              void* d_out, int out_size, void* d_ws, size_t ws_size,
                              hipStream_t stream) {
    const float* X      = (const float*)d_in[0];
    const void*  mask   = d_in[1];
    const float* W      = (const float*)d_in[2];
    const float* bias   = (const float*)d_in[3];
    const float* startT = (const float*)d_in[4];
    const float* endT   = (const float*)d_in[5];
    const float* trans  = (const float*)d_in[6];

    float* em   = (float*)d_out;
    float* pred = (float*)d_out + (size_t)BB * TT * KK;

    emission_kernel<<<(BB * TT) / BM, 256, 0, stream>>>(X, W, bias, em);

    const size_t SH_BYTES = (size_t)BB * TT * KK * sizeof(float);   // 8 MB
    const size_t HI_BYTES = (size_t)BB * TT * KK;                   // 2 MB
    const size_t NEED = SH_BYTES + HI_BYTES + 256;

    if (ws_size >= NEED) {
        float* shist = (float*)d_ws;
        uchar* histg = (uchar*)d_ws + SH_BYTES;
        int*   btarr = (int*)((uchar*)d_ws + SH_BYTES + HI_BYTES);
        viterbi_fwd<<<BB / 8, 512, 0, stream>>>(em, mask, startT, endT, trans, shist, btarr);
        hist_kernel<<<BB * 64, 256, 0, stream>>>(em, mask, trans, shist, histg);
        viterbi_bt<<<BB, 256, 0, stream>>>(histg, btarr, pred);
    } else {
        viterbi_kernel<<<BB, 256, 0, stream>>>(em, mask, startT, endT, trans, pred);
    }
}

// Round 17
// 243.318 us; speedup vs baseline: 1.7738x; 1.7738x over previous
//
#include <hip/hip_runtime.h>
#include <hip/hip_bf16.h>

#define BB 64
#define TT 512
#define FF 1024
#define KK 64

typedef unsigned char uchar;

// ---------------- Emission GEMM (round-1 version, measured ~83-88us, 6x) ----------------
#define BM 64
#define BF 64
#define LDA 68

__global__ __launch_bounds__(256)
void emission_kernel(const float* __restrict__ X, const float* __restrict__ W,
                     const float* __restrict__ bias, float* __restrict__ em)
{
    __shared__ float As[BF][LDA];
    __shared__ float Bs[BF][LDA];
    const int tid = threadIdx.x;
    const int row0 = blockIdx.x * BM;
    const int tm = tid & 15;
    const int tn = tid >> 4;
    const int lq = tid & 15;
    const int lr = tid >> 4;

    float acc[4][4];
#pragma unroll
    for (int i = 0; i < 4; ++i)
#pragma unroll
        for (int jj = 0; jj < 4; ++jj) acc[i][jj] = 0.f;

    for (int f0 = 0; f0 < FF; f0 += BF) {
#pragma unroll
        for (int p = 0; p < 4; ++p) {
            const int r = p * 16 + lr;
            float4 a = *(const float4*)(X + (size_t)(row0 + r) * FF + f0 + lq * 4);
            As[lq * 4 + 0][r] = a.x;
            As[lq * 4 + 1][r] = a.y;
            As[lq * 4 + 2][r] = a.z;
            As[lq * 4 + 3][r] = a.w;
            float4 w = *(const float4*)(W + (size_t)r * FF + f0 + lq * 4);
            Bs[lq * 4 + 0][r] = w.x;
            Bs[lq * 4 + 1][r] = w.y;
            Bs[lq * 4 + 2][r] = w.z;
            Bs[lq * 4 + 3][r] = w.w;
        }
        __syncthreads();
#pragma unroll
        for (int f = 0; f < BF; ++f) {
            float4 a = *(const float4*)&As[f][tm * 4];
            float4 b = *(const float4*)&Bs[f][tn * 4];
            acc[0][0] += a.x * b.x; acc[0][1] += a.x * b.y; acc[0][2] += a.x * b.z; acc[0][3] += a.x * b.w;
            acc[1][0] += a.y * b.x; acc[1][1] += a.y * b.y; acc[1][2] += a.y * b.z; acc[1][3] += a.y * b.w;
            acc[2][0] += a.z * b.x; acc[2][1] += a.z * b.y; acc[2][2] += a.z * b.z; acc[2][3] += a.z * b.w;
            acc[3][0] += a.w * b.x; acc[3][1] += a.w * b.y; acc[3][2] += a.w * b.z; acc[3][3] += a.w * b.w;
        }
        __syncthreads();
    }

    const float4 b4 = *(const float4*)(bias + tn * 4);
#pragma unroll
    for (int i = 0; i < 4; ++i) {
        float4 o;
        o.x = acc[i][0] + b4.x;
        o.y = acc[i][1] + b4.y;
        o.z = acc[i][2] + b4.z;
        o.w = acc[i][3] + b4.w;
        *(float4*)(em + (size_t)(row0 + tm * 4 + i) * KK + tn * 4) = o;
    }
}

// ---------------- Forward: value-only recurrence, 1 wave/seq ----------------
// r10-r16 synthesis: the per-step wall is the 64 v_readlane ops issuing at
// ~4cy on a shared SIMD port (r16: 2 waves/SIMD exactly halved per-wave rate).
// Fix: broadcast score via LDS instead — 1 ds_write_b32 + 16 UNIFORM-address
// ds_read_b128 (uniform addr = hardware broadcast, conflict-free). Double-
// buffered sbuf[2][64]; the write for step t+1 is issued right after score is
// computed, so the global sb-store + loop bookkeeping hides the write->read
// latency. tc[64] pinned in VGPRs (r11 regime: waves_per_eu(1,1) + asm pins —
// r7's version of this died only because it predated the register-regime fix).
#define VSTEP(EV, TIDX) do {                                                   \
    const float* sp = &sbuf[(TIDX) & 1][0];                                    \
    float m_;                                                                  \
    _Pragma("unroll")                                                          \
    for (int c = 0; c < 8; ++c) {                                              \
        const float4 s0 = *(const float4*)(sp + c * 8);                        \
        const float4 s1 = *(const float4*)(sp + c * 8 + 4);                    \
        const float v0 = s0.x + tc[c * 8 + 0];                                 \
        const float v1 = s0.y + tc[c * 8 + 1];                                 \
        const float v2 = s0.z + tc[c * 8 + 2];                                 \
        const float v3 = s0.w + tc[c * 8 + 3];                                 \
        const float v4 = s1.x + tc[c * 8 + 4];                                 \
        const float v5 = s1.y + tc[c * 8 + 5];                                 \
        const float v6 = s1.z + tc[c * 8 + 6];                                 \
        const float v7 = s1.w + tc[c * 8 + 7];                                 \
        const float ma = fmaxf(fmaxf(v0, v1), v2);   /* v_max3 */              \
        const float mb = fmaxf(fmaxf(v3, v4), v5);                             \
        const float mc = fmaxf(fmaxf(v6, v7), ma);                             \
        const float w_ = fmaxf(mb, mc);                                        \
        m_ = (c == 0) ? w_ : fmaxf(m_, w_);                                    \
    }                                                                          \
    score = m_ + (EV);                                                         \
    sbuf[((TIDX) + 1) & 1][j] = score;   /* next step's broadcast, early */    \
    sb[(size_t)(TIDX) * KK + j] = score;                                       \
} while (0)

#define RLANE(I) __uint_as_float((unsigned)__builtin_amdgcn_readlane((int)__float_as_uint(score), (I)))

__global__ __launch_bounds__(64)
__attribute__((amdgpu_waves_per_eu(1, 1)))
void viterbi_fwd(const float* __restrict__ em, const void* __restrict__ maskp,
                 const float* __restrict__ startT, const float* __restrict__ endT,
                 const float* __restrict__ trans, float* __restrict__ shist,
                 int* __restrict__ btarr)
{
    __shared__ float sbuf[2][KK];   // score broadcast, double-buffered by t&1

    const int b = blockIdx.x;
    const int j = threadIdx.x;

    const uchar* m8 = (const uchar*)maskp;
    const int* m32 = (const int*)maskp;
    const bool u8m = (m8[1] != 0);

    // ---- length precompute (mask is monotone: true for t < len) ----
    int myc;
    if (u8m) {
        const uint2 mv = *(const uint2*)(m8 + (size_t)b * TT + j * 8);
        const unsigned s4 = (mv.x & 0x01010101u) + (mv.y & 0x01010101u);
        myc = (int)((s4 * 0x01010101u) >> 24);
    } else {
        const int* mp = m32 + (size_t)b * TT + j * 8;
        const int4 a = *(const int4*)mp;
        const int4 c = *(const int4*)(mp + 4);
        myc = (a.x != 0) + (a.y != 0) + (a.z != 0) + (a.w != 0)
            + (c.x != 0) + (c.y != 0) + (c.z != 0) + (c.w != 0);
    }
#pragma unroll
    for (int o = 1; o < 64; o <<= 1) myc += __shfl_xor(myc, o, 64);
    const int len = myc;   // valid timesteps; loop runs t = 1..len-1

    float tc[KK];
#pragma unroll
    for (int i = 0; i < KK; ++i) tc[i] = trans[i * KK + j];
    // PIN: opaque asm result -> loads cannot be rematerialized in-loop
#pragma unroll
    for (int i = 0; i < KK; ++i) asm volatile("" : "+v"(tc[i]));

    const float* emb = em + (size_t)b * TT * KK;
    float* sb = shist + (size_t)b * TT * KK;

    float score = startT[j] + emb[j];   // t = 0
    sb[j] = score;
    sbuf[1][j] = score;                 // t = 1 reads sbuf[1&1]

    // named prefetch slots: eA..eD hold e for t, t+1, t+2, t+3
    float eA = emb[1 * KK + j];
    float eB = emb[2 * KK + j];
    float eC = emb[3 * KK + j];
    float eD = emb[4 * KK + j];

    int t = 1;
    for (; t + 3 < len; t += 4) {
        VSTEP(eA, t);     eA = emb[(size_t)((t + 4 < TT) ? t + 4 : TT - 1) * KK + j];
        VSTEP(eB, t + 1); eB = emb[(size_t)((t + 5 < TT) ? t + 5 : TT - 1) * KK + j];
        VSTEP(eC, t + 2); eC = emb[(size_t)((t + 6 < TT) ? t + 6 : TT - 1) * KK + j];
        VSTEP(eD, t + 3); eD = emb[(size_t)((t + 7 < TT) ? t + 7 : TT - 1) * KK + j];
    }
    for (; t < len; ++t) {   // tail 0-3 steps
        VSTEP(eA, t);
        eA = eB; eB = eC; eC = eD;
    }

    score += endT[j];
    // one-time first-index argmax over lanes
    float bm = -__builtin_inff();
    int bt = 0;
#pragma unroll
    for (int i = 0; i < KK; ++i) {
        const float si = RLANE(i);
        if (si > bm) { bm = si; bt = i; }
    }
    if (j == 0) btarr[b] = bt;
}

// ---------------- hist recompute: massively parallel (validated r8-r16) ----------------
__global__ __launch_bounds__(256)
void hist_kernel(const float* __restrict__ em, const void* __restrict__ maskp,
                 const float* __restrict__ trans, const float* __restrict__ shist,
                 uchar* __restrict__ histg)
{
    const int tid = threadIdx.x;
    const int bid = blockIdx.x;
    const int b = bid >> 6;
    const int t0 = (bid & 63) * 8;

    __shared__ float tl[64][65];
    __shared__ float srow[8][64];

    const uchar* m8 = (const uchar*)maskp;
    const int* m32 = (const int*)maskp;
    const bool u8m = (m8[1] != 0);

#pragma unroll
    for (int p = 0; p < 16; ++p) {
        const int idx = p * 256 + tid;
        tl[idx >> 6][idx & 63] = trans[idx];
    }
#pragma unroll
    for (int p = 0; p < 2; ++p) {
        const int idx = p * 256 + tid;
        const int r = idx >> 6, i2 = idx & 63;
        const int ts = t0 - 1 + r;
        srow[r][i2] = (ts >= 0) ? shist[((size_t)b * TT + ts) * KK + i2] : 0.f;
    }
    __syncthreads();

    const int j = tid & 63;
    const int tq = tid >> 6;

#pragma unroll
    for (int half = 0; half < 2; ++half) {
        const int toff = tq * 2 + half;
        const int t = t0 + toff;
        if (t == 0) continue;
        const int mt = u8m ? (int)m8[b * TT + t] : m32[b * TT + t];
        uchar hv;
        if (!mt) {
            hv = (uchar)j;
        } else {
            const float e = em[((size_t)b * TT + t) * KK + j];
            const float* sr = &srow[toff][0];
            float bm = -__builtin_inff();
            int bi = 0;
#pragma unroll 16
            for (int i = 0; i < KK; ++i) {
                const float cand = (sr[i] + tl[i][j]) + e;   // reference order
                if (cand > bm) { bm = cand; bi = i; }        // strict >: first index
            }
            hv = (uchar)bi;
        }
        histg[((size_t)b * TT + t) * KK + j] = hv;
    }
}

// ---------------- Backtrack (validated r8-r16) ----------------
__global__ __launch_bounds__(256)
void viterbi_bt(const uchar* __restrict__ histg, const int* __restrict__ btarr,
                float* __restrict__ pred)
{
    const int b = blockIdx.x;
    const int tid = threadIdx.x;
    const int w = tid >> 6;
    const int j = tid & 63;

    __shared__ uchar hist[TT][KK];
    __shared__ uchar hypo[8][64][64];

    const uint4* src = (const uint4*)(histg + (size_t)b * TT * KK);
    uint4* dst = (uint4*)&hist[0][0];
#pragma unroll
    for (int p = 0; p < 8; ++p) dst[p * 256 + tid] = src[p * 256 + tid];
    __syncthreads();

    const int bt = btarr[b];

#pragma unroll
    for (int ss = 0; ss < 2; ++ss) {
        const int s = w * 2 + ss;
        int tag = j;
        if (s == 7) {
            hypo[7][63][j] = (uchar)j;
            for (int t = TT - 1; t >= 7 * 64 + 1; --t) {
                tag = hist[t][tag];
                hypo[7][t - 1 - 7 * 64][j] = (uchar)tag;
            }
        } else {
            for (int t = (s + 1) * 64; t >= s * 64 + 1; --t) {
                tag = hist[t][tag];
                hypo[s][t - 1 - s * 64][j] = (uchar)tag;
            }
        }
    }
    __syncthreads();

    int rows_[8];
    rows_[7] = bt;
#pragma unroll
    for (int s = 6; s >= 0; --s) rows_[s] = hypo[s + 1][0][rows_[s + 1]];

    float* pb = pred + (size_t)b * TT;
#pragma unroll
    for (int ss = 0; ss < 2; ++ss) {
        const int s = w * 2 + ss;
        pb[s * 64 + j] = (float)hypo[s][j][rows_[s]];
    }
}

// ---------------- Fallback monolithic viterbi (round-6, proven) ----------------
__global__ __launch_bounds__(256)
void viterbi_kernel(const float* __restrict__ em, const void* __restrict__ maskp,
                    const float* __restrict__ startT, const float* __restrict__ endT,
                    const float* __restrict__ trans, float* __restrict__ pred)
{
    const int b = blockIdx.x;
    const int tid = threadIdx.x;
    const int w = tid >> 6;
    const int j = tid & 63;

    __shared__ uchar hist[TT][KK];
    __shared__ uchar hypo[8][64][64];
    __shared__ int bt_sh;

    const uchar* m8 = (const uchar*)maskp;
    const int* m32 = (const int*)maskp;
    const bool u8m = (m8[1] != 0);

    if (w == 0) {
        float tc[KK];
#pragma unroll
        for (int i = 0; i < KK; ++i) tc[i] = trans[i * KK + j];

        const float* emb = em + (size_t)b * TT * KK;
        float score = startT[j] + emb[j];
        const float endv = endT[j];

        float e_cur = emb[KK + j];
        int   m_cur = u8m ? (int)m8[b * TT + 1] : m32[b * TT + 1];

        int t = 1;
        for (; t < TT; ++t) {
            const int tn2 = (t + 1 < TT) ? (t + 1) : (TT - 1);
            const float e_next = emb[(size_t)tn2 * KK + j];
            const int   m_next = u8m ? (int)m8[b * TT + tn2] : m32[b * TT + tn2];
            if (!m_cur) break;
            float m = -__builtin_inff();
            int idx = 0;
#pragma unroll
            for (int i = 0; i < KK; ++i) {
                const float si = __uint_as_float(__builtin_amdgcn_readlane(__float_as_uint(score), i));
                const float v = (si + tc[i]) + e_cur;
                if (v > m) { m = v; idx = i; }
            }
            score = m;
            hist[t][j] = (uchar)idx;
            e_cur = e_next; m_cur = m_next;
        }
        for (; t < TT; ++t) hist[t][j] = (uchar)j;

        score += endv;
        float bm = -__builtin_inff();
        int bt = 0;
#pragma unroll
        for (int i = 0; i < KK; ++i) {
            const float si = __uint_as_float(__builtin_amdgcn_readlane(__float_as_uint(score), i));
            if (si > bm) { bm = si; bt = i; }
        }
        if (j == 0) bt_sh = bt;
    }
    __syncthreads();

#pragma unroll
    for (int ss = 0; ss < 2; ++ss) {
        const int s = w * 2 + ss;
        int tag = j;
        if (s == 7) {
            hypo[7][63][j] = (uchar)j;
            for (int t = TT - 1; t >= 7 * 64 + 1; --t) {
                tag = hist[t][tag];
                hypo[7][t - 1 - 7 * 64][j] = (uchar)tag;
            }
        } else {
            for (int t = (s + 1) * 64; t >= s * 64 + 1; --t) {
                tag = hist[t][tag];
                hypo[s][t - 1 - s * 64][j] = (uchar)tag;
            }
        }
    }
    __syncthreads();

    const int bt = bt_sh;
    int rows_[8];
    rows_[7] = bt;
#pragma unroll
    for (int s = 6; s >= 0; --s) rows_[s] = hypo[s + 1][0][rows_[s + 1]];

    float* pb = pred + (size_t)b * TT;
#pragma unroll
    for (int ss = 0; ss < 2; ++ss) {
        const int s = w * 2 + ss;
        pb[s * 64 + j] = (float)hypo[s][j][rows_[s]];
    }
}

extern "C" void kernel_launch(void* const* d_in, const int* in_sizes, int n_in,
                              void* d_out, int out_size, void* d_ws, size_t ws_size,
                              hipStream_t stream) {
    const float* X      = (const float*)d_in[0];
    const void*  mask   = d_in[1];
    const float* W      = (const float*)d_in[2];
    const float* bias   = (const float*)d_in[3];
    const float* startT = (const float*)d_in[4];
    const float* endT   = (const float*)d_in[5];
    const float* trans  = (const float*)d_in[6];

    float* em   = (float*)d_out;
    float* pred = (float*)d_out + (size_t)BB * TT * KK;

    emission_kernel<<<(BB * TT) / BM, 256, 0, stream>>>(X, W, bias, em);

    const size_t SH_BYTES = (size_t)BB * TT * KK * sizeof(float);   // 8 MB
    const size_t HI_BYTES = (size_t)BB * TT * KK;                   // 2 MB
    const size_t NEED = SH_BYTES + HI_BYTES + 256;

    if (ws_size >= NEED) {
        float* shist = (float*)d_ws;
        uchar* histg = (uchar*)d_ws + SH_BYTES;
        int*   btarr = (int*)((uchar*)d_ws + SH_BYTES + HI_BYTES);
        viterbi_fwd<<<BB, 64, 0, stream>>>(em, mask, startT, endT, trans, shist, btarr);
        hist_kernel<<<BB * 64, 256, 0, stream>>>(em, mask, trans, shist, histg);
        viterbi_bt<<<BB, 256, 0, stream>>>(histg, btarr, pred);
    } else {
        viterbi_kernel<<<BB, 256, 0, stream>>>(em, mask, startT, endT, trans, pred);
    }
}

// Round 18
// 233.508 us; speedup vs baseline: 1.8483x; 1.0420x over previous
//
#include <hip/hip_runtime.h>
#include <hip/hip_bf16.h>

#define BB 64
#define TT 512
#define FF 1024
#define KK 64

typedef unsigned char uchar;
typedef float float2v __attribute__((ext_vector_type(2)));
typedef float wv16 __attribute__((ext_vector_type(16)));

// ---------------- W transpose: WT[f][c] = W[c][f]  (256 KB in d_ws) ----------------
__global__ __launch_bounds__(256)
void wt_kernel(const float* __restrict__ W, float* __restrict__ WT)
{
    const int idx = blockIdx.x * 256 + threadIdx.x;   // 0..65535
    const int c = idx >> 10;
    const int f = idx & 1023;
    WT[(size_t)f * KK + c] = W[idx];
}

// ---------------- Emission v2: lane=row, wave=16 cols, A^T in LDS (b32), WT uniform ----
// Old kernel was LDS-instr-bound (16384 b128/CU x 12cy = 82us). Here: 1 conflict-free
// ds_read_b32 per f per wave (banks (f+r)%32, pad 65) + one 64B wave-uniform WT load
// (readfirstlane -> scalar-load path). Arithmetic: identical ascending-f fmac chain.
__global__ __launch_bounds__(256)
void emission2_kernel(const float* __restrict__ X, const float* __restrict__ WT,
                      const float* __restrict__ bias, float* __restrict__ em)
{
    __shared__ float As[64][65];   // As[f_local][row]
    const int tid = threadIdx.x;
    const int row0 = blockIdx.x * 64;
    const int lane = tid & 63;
    const int cw = 16 * (int)__builtin_amdgcn_readfirstlane(tid >> 6);  // wave col base

    const int sr = tid >> 2;       // staging row 0..63
    const int sq = tid & 3;        // staging f4 group

    float acc[16];
#pragma unroll
    for (int c = 0; c < 16; ++c) acc[c] = 0.f;

    for (int f0 = 0; f0 < FF; f0 += 64) {
#pragma unroll
        for (int p = 0; p < 4; ++p) {
            const int fl = p * 16 + sq * 4;
            const float4 a = *(const float4*)(X + (size_t)(row0 + sr) * FF + f0 + fl);
            As[fl + 0][sr] = a.x;
            As[fl + 1][sr] = a.y;
            As[fl + 2][sr] = a.z;
            As[fl + 3][sr] = a.w;
        }
        __syncthreads();
#pragma unroll 16
        for (int f = 0; f < 64; ++f) {
            const float av = As[f][lane];
            const wv16 bv = *(const wv16*)(WT + (size_t)(f0 + f) * KK + cw);
#pragma unroll
            for (int c = 0; c < 16; ++c) acc[c] = fmaf(av, bv[c], acc[c]);
        }
        __syncthreads();
    }

    const float4 b0 = *(const float4*)(bias + cw);
    const float4 b1 = *(const float4*)(bias + cw + 4);
    const float4 b2 = *(const float4*)(bias + cw + 8);
    const float4 b3 = *(const float4*)(bias + cw + 12);
    float* outp = em + (size_t)(row0 + lane) * KK + cw;
    float4 o;
    o.x = acc[0] + b0.x;  o.y = acc[1] + b0.y;  o.z = acc[2] + b0.z;  o.w = acc[3] + b0.w;
    *(float4*)(outp + 0) = o;
    o.x = acc[4] + b1.x;  o.y = acc[5] + b1.y;  o.z = acc[6] + b1.z;  o.w = acc[7] + b1.w;
    *(float4*)(outp + 4) = o;
    o.x = acc[8] + b2.x;  o.y = acc[9] + b2.y;  o.z = acc[10] + b2.z; o.w = acc[11] + b2.w;
    *(float4*)(outp + 8) = o;
    o.x = acc[12] + b3.x; o.y = acc[13] + b3.y; o.z = acc[14] + b3.z; o.w = acc[15] + b3.w;
    *(float4*)(outp + 12) = o;
}

// ---------------- Emission v1 (fallback path only) ----------------
#define BM 64
#define BF 64
#define LDA 68

__global__ __launch_bounds__(256)
void emission_kernel(const float* __restrict__ X, const float* __restrict__ W,
                     const float* __restrict__ bias, float* __restrict__ em)
{
    __shared__ float As[BF][LDA];
    __shared__ float Bs[BF][LDA];
    const int tid = threadIdx.x;
    const int row0 = blockIdx.x * BM;
    const int tm = tid & 15;
    const int tn = tid >> 4;
    const int lq = tid & 15;
    const int lr = tid >> 4;

    float acc[4][4];
#pragma unroll
    for (int i = 0; i < 4; ++i)
#pragma unroll
        for (int jj = 0; jj < 4; ++jj) acc[i][jj] = 0.f;

    for (int f0 = 0; f0 < FF; f0 += BF) {
#pragma unroll
        for (int p = 0; p < 4; ++p) {
            const int r = p * 16 + lr;
            float4 a = *(const float4*)(X + (size_t)(row0 + r) * FF + f0 + lq * 4);
            As[lq * 4 + 0][r] = a.x;
            As[lq * 4 + 1][r] = a.y;
            As[lq * 4 + 2][r] = a.z;
            As[lq * 4 + 3][r] = a.w;
            float4 w = *(const float4*)(W + (size_t)r * FF + f0 + lq * 4);
            Bs[lq * 4 + 0][r] = w.x;
            Bs[lq * 4 + 1][r] = w.y;
            Bs[lq * 4 + 2][r] = w.z;
            Bs[lq * 4 + 3][r] = w.w;
        }
        __syncthreads();
#pragma unroll
        for (int f = 0; f < BF; ++f) {
            float4 a = *(const float4*)&As[f][tm * 4];
            float4 b = *(const float4*)&Bs[f][tn * 4];
            acc[0][0] += a.x * b.x; acc[0][1] += a.x * b.y; acc[0][2] += a.x * b.z; acc[0][3] += a.x * b.w;
            acc[1][0] += a.y * b.x; acc[1][1] += a.y * b.y; acc[1][2] += a.y * b.z; acc[1][3] += a.y * b.w;
            acc[2][0] += a.z * b.x; acc[2][1] += a.z * b.y; acc[2][2] += a.z * b.z; acc[2][3] += a.z * b.w;
            acc[3][0] += a.w * b.x; acc[3][1] += a.w * b.y; acc[3][2] += a.w * b.z; acc[3][3] += a.w * b.w;
        }
        __syncthreads();
    }

    const float4 b4 = *(const float4*)(bias + tn * 4);
#pragma unroll
    for (int i = 0; i < 4; ++i) {
        float4 o;
        o.x = acc[i][0] + b4.x;
        o.y = acc[i][1] + b4.y;
        o.z = acc[i][2] + b4.z;
        o.w = acc[i][3] + b4.w;
        *(float4*)(em + (size_t)(row0 + tm * 4 + i) * KK + tn * 4) = o;
    }
}

// ---------------- Forward: value-only, LDS-broadcast (r17) + packed adds ----------------
// r17 win: LDS uniform-address broadcast beats readlane (620 vs 759 cy/step).
// This round: 64 scalar v_add -> 32 v_pk_add_f32 via float2 ext-vectors
// (instr count ~109 -> ~77 per step). tc as pinned float2 pairs.
#define VSTEP(EV, TIDX) do {                                                   \
    const float2v* sp2 = (const float2v*)&sbuf[(TIDX) & 1][0];                 \
    float m_;                                                                  \
    _Pragma("unroll")                                                          \
    for (int c = 0; c < 8; ++c) {                                              \
        const float2v p0 = sp2[c * 4 + 0] + tc2[c * 4 + 0];                    \
        const float2v p1 = sp2[c * 4 + 1] + tc2[c * 4 + 1];                    \
        const float2v p2 = sp2[c * 4 + 2] + tc2[c * 4 + 2];                    \
        const float2v p3 = sp2[c * 4 + 3] + tc2[c * 4 + 3];                    \
        const float ma = fmaxf(fmaxf(p0.x, p0.y), p1.x);   /* v_max3 */        \
        const float mb = fmaxf(fmaxf(p1.y, p2.x), p2.y);                       \
        const float mc = fmaxf(fmaxf(p3.x, p3.y), ma);                         \
        const float w_ = fmaxf(mb, mc);                                        \
        m_ = (c == 0) ? w_ : fmaxf(m_, w_);                                    \
    }                                                                          \
    score = m_ + (EV);                                                         \
    sbuf[((TIDX) + 1) & 1][j] = score;   /* next step's broadcast, early */    \
    sb[(size_t)(TIDX) * KK + j] = score;                                       \
} while (0)

#define RLANE(I) __uint_as_float((unsigned)__builtin_amdgcn_readlane((int)__float_as_uint(score), (I)))

__global__ __launch_bounds__(64)
__attribute__((amdgpu_waves_per_eu(1, 1)))
void viterbi_fwd(const float* __restrict__ em, const void* __restrict__ maskp,
                 const float* __restrict__ startT, const float* __restrict__ endT,
                 const float* __restrict__ trans, float* __restrict__ shist,
                 int* __restrict__ btarr)
{
    __shared__ float sbuf[2][KK];

    const int b = blockIdx.x;
    const int j = threadIdx.x;

    const uchar* m8 = (const uchar*)maskp;
    const int* m32 = (const int*)maskp;
    const bool u8m = (m8[1] != 0);

    // ---- length precompute (mask monotone: true for t < len) ----
    int myc;
    if (u8m) {
        const uint2 mv = *(const uint2*)(m8 + (size_t)b * TT + j * 8);
        const unsigned s4 = (mv.x & 0x01010101u) + (mv.y & 0x01010101u);
        myc = (int)((s4 * 0x01010101u) >> 24);
    } else {
        const int* mp = m32 + (size_t)b * TT + j * 8;
        const int4 a = *(const int4*)mp;
        const int4 c = *(const int4*)(mp + 4);
        myc = (a.x != 0) + (a.y != 0) + (a.z != 0) + (a.w != 0)
            + (c.x != 0) + (c.y != 0) + (c.z != 0) + (c.w != 0);
    }
#pragma unroll
    for (int o = 1; o < 64; o <<= 1) myc += __shfl_xor(myc, o, 64);
    const int len = myc;

    // trans column as 32 float2 pairs, pinned in VGPRs (r11 regime)
    float2v tc2[32];
#pragma unroll
    for (int i = 0; i < 32; ++i) {
        tc2[i].x = trans[(2 * i) * KK + j];
        tc2[i].y = trans[(2 * i + 1) * KK + j];
    }
#pragma unroll
    for (int i = 0; i < 32; ++i) asm volatile("" : "+v"(tc2[i]));

    const float* emb = em + (size_t)b * TT * KK;
    float* sb = shist + (size_t)b * TT * KK;

    float score = startT[j] + emb[j];   // t = 0
    sb[j] = score;
    sbuf[1][j] = score;                 // t = 1 reads sbuf[1&1]

    float eA = emb[1 * KK + j];
    float eB = emb[2 * KK + j];
    float eC = emb[3 * KK + j];
    float eD = emb[4 * KK + j];

    int t = 1;
    for (; t + 3 < len; t += 4) {
        VSTEP(eA, t);     eA = emb[(size_t)((t + 4 < TT) ? t + 4 : TT - 1) * KK + j];
        VSTEP(eB, t + 1); eB = emb[(size_t)((t + 5 < TT) ? t + 5 : TT - 1) * KK + j];
        VSTEP(eC, t + 2); eC = emb[(size_t)((t + 6 < TT) ? t + 6 : TT - 1) * KK + j];
        VSTEP(eD, t + 3); eD = emb[(size_t)((t + 7 < TT) ? t + 7 : TT - 1) * KK + j];
    }
    for (; t < len; ++t) {
        VSTEP(eA, t);
        eA = eB; eB = eC; eC = eD;
    }

    score += endT[j];
    float bm = -__builtin_inff();
    int bt = 0;
#pragma unroll
    for (int i = 0; i < KK; ++i) {
        const float si = RLANE(i);
        if (si > bm) { bm = si; bt = i; }
    }
    if (j == 0) btarr[b] = bt;
}

// ---------------- hist recompute: massively parallel (validated r8-r17) ----------------
__global__ __launch_bounds__(256)
void hist_kernel(const float* __restrict__ em, const void* __restrict__ maskp,
                 const float* __restrict__ trans, const float* __restrict__ shist,
                 uchar* __restrict__ histg)
{
    const int tid = threadIdx.x;
    const int bid = blockIdx.x;
    const int b = bid >> 6;
    const int t0 = (bid & 63) * 8;

    __shared__ float tl[64][65];
    __shared__ float srow[8][64];

    const uchar* m8 = (const uchar*)maskp;
    const int* m32 = (const int*)maskp;
    const bool u8m = (m8[1] != 0);

#pragma unroll
    for (int p = 0; p < 16; ++p) {
        const int idx = p * 256 + tid;
        tl[idx >> 6][idx & 63] = trans[idx];
    }
#pragma unroll
    for (int p = 0; p < 2; ++p) {
        const int idx = p * 256 + tid;
        const int r = idx >> 6, i2 = idx & 63;
        const int ts = t0 - 1 + r;
        srow[r][i2] = (ts >= 0) ? shist[((size_t)b * TT + ts) * KK + i2] : 0.f;
    }
    __syncthreads();

    const int j = tid & 63;
    const int tq = tid >> 6;

#pragma unroll
    for (int half = 0; half < 2; ++half) {
        const int toff = tq * 2 + half;
        const int t = t0 + toff;
        if (t == 0) continue;
        const int mt = u8m ? (int)m8[b * TT + t] : m32[b * TT + t];
        uchar hv;
        if (!mt) {
            hv = (uchar)j;
        } else {
            const float e = em[((size_t)b * TT + t) * KK + j];
            const float* sr = &srow[toff][0];
            float bm = -__builtin_inff();
            int bi = 0;
#pragma unroll 16
            for (int i = 0; i < KK; ++i) {
                const float cand = (sr[i] + tl[i][j]) + e;   // reference order
                if (cand > bm) { bm = cand; bi = i; }        // strict >: first index
            }
            hv = (uchar)bi;
        }
        histg[((size_t)b * TT + t) * KK + j] = hv;
    }
}

// ---------------- Backtrack (validated r8-r17) ----------------
__global__ __launch_bounds__(256)
void viterbi_bt(const uchar* __restrict__ histg, const int* __restrict__ btarr,
                float* __restrict__ pred)
{
    const int b = blockIdx.x;
    const int tid = threadIdx.x;
    const int w = tid >> 6;
    const int j = tid & 63;

    __shared__ uchar hist[TT][KK];
    __shared__ uchar hypo[8][64][64];

    const uint4* src = (const uint4*)(histg + (size_t)b * TT * KK);
    uint4* dst = (uint4*)&hist[0][0];
#pragma unroll
    for (int p = 0; p < 8; ++p) dst[p * 256 + tid] = src[p * 256 + tid];
    __syncthreads();

    const int bt = btarr[b];

#pragma unroll
    for (int ss = 0; ss < 2; ++ss) {
        const int s = w * 2 + ss;
        int tag = j;
        if (s == 7) {
            hypo[7][63][j] = (uchar)j;
            for (int t = TT - 1; t >= 7 * 64 + 1; --t) {
                tag = hist[t][tag];
                hypo[7][t - 1 - 7 * 64][j] = (uchar)tag;
            }
        } else {
            for (int t = (s + 1) * 64; t >= s * 64 + 1; --t) {
                tag = hist[t][tag];
                hypo[s][t - 1 - s * 64][j] = (uchar)tag;
            }
        }
    }
    __syncthreads();

    int rows_[8];
    rows_[7] = bt;
#pragma unroll
    for (int s = 6; s >= 0; --s) rows_[s] = hypo[s + 1][0][rows_[s + 1]];

    float* pb = pred + (size_t)b * TT;
#pragma unroll
    for (int ss = 0; ss < 2; ++ss) {
        const int s = w * 2 + ss;
        pb[s * 64 + j] = (float)hypo[s][j][rows_[s]];
    }
}

// ---------------- Fallback monolithic viterbi (round-6, proven) ----------------
__global__ __launch_bounds__(256)
void viterbi_kernel(const float* __restrict__ em, const void* __restrict__ maskp,
                    const float* __restrict__ startT, const float* __restrict__ endT,
                    const float* __restrict__ trans, float* __restrict__ pred)
{
    const int b = blockIdx.x;
    const int tid = threadIdx.x;
    const int w = tid >> 6;
    const int j = tid & 63;

    __shared__ uchar hist[TT][KK];
    __shared__ uchar hypo[8][64][64];
    __shared__ int bt_sh;

    const uchar* m8 = (const uchar*)maskp;
    const int* m32 = (const int*)maskp;
    const bool u8m = (m8[1] != 0);

    if (w == 0) {
        float tc[KK];
#pragma unroll
        for (int i = 0; i < KK; ++i) tc[i] = trans[i * KK + j];

        const float* emb = em + (size_t)b * TT * KK;
        float score = startT[j] + emb[j];
        const float endv = endT[j];

        float e_cur = emb[KK + j];
        int   m_cur = u8m ? (int)m8[b * TT + 1] : m32[b * TT + 1];

        int t = 1;
        for (; t < TT; ++t) {
            const int tn2 = (t + 1 < TT) ? (t + 1) : (TT - 1);
            const float e_next = emb[(size_t)tn2 * KK + j];
            const int   m_next = u8m ? (int)m8[b * TT + tn2] : m32[b * TT + tn2];
            if (!m_cur) break;
            float m = -__builtin_inff();
            int idx = 0;
#pragma unroll
            for (int i = 0; i < KK; ++i) {
                const float si = __uint_as_float(__builtin_amdgcn_readlane(__float_as_uint(score), i));
                const float v = (si + tc[i]) + e_cur;
                if (v > m) { m = v; idx = i; }
            }
            score = m;
            hist[t][j] = (uchar)idx;
            e_cur = e_next; m_cur = m_next;
        }
        for (; t < TT; ++t) hist[t][j] = (uchar)j;

        score += endv;
        float bm = -__builtin_inff();
        int bt = 0;
#pragma unroll
        for (int i = 0; i < KK; ++i) {
            const float si = __uint_as_float(__builtin_amdgcn_readlane(__float_as_uint(score), i));
            if (si > bm) { bm = si; bt = i; }
        }
        if (j == 0) bt_sh = bt;
    }
    __syncthreads();

#pragma unroll
    for (int ss = 0; ss < 2; ++ss) {
        const int s = w * 2 + ss;
        int tag = j;
        if (s == 7) {
            hypo[7][63][j] = (uchar)j;
            for (int t = TT - 1; t >= 7 * 64 + 1; --t) {
                tag = hist[t][tag];
                hypo[7][t - 1 - 7 * 64][j] = (uchar)tag;
            }
        } else {
            for (int t = (s + 1) * 64; t >= s * 64 + 1; --t) {
                tag = hist[t][tag];
                hypo[s][t - 1 - s * 64][j] = (uchar)tag;
            }
        }
    }
    __syncthreads();

    const int bt = bt_sh;
    int rows_[8];
    rows_[7] = bt;
#pragma unroll
    for (int s = 6; s >= 0; --s) rows_[s] = hypo[s + 1][0][rows_[s + 1]];

    float* pb = pred + (size_t)b * TT;
#pragma unroll
    for (int ss = 0; ss < 2; ++ss) {
        const int s = w * 2 + ss;
        pb[s * 64 + j] = (float)hypo[s][j][rows_[s]];
    }
}

extern "C" void kernel_launch(void* const* d_in, const int* in_sizes, int n_in,
                              void* d_out, int out_size, void* d_ws, size_t ws_size,
                              hipStream_t stream) {
    const float* X      = (const float*)d_in[0];
    const void*  mask   = d_in[1];
    const float* W      = (const float*)d_in[2];
    const float* bias   = (const float*)d_in[3];
    const float* startT = (const float*)d_in[4];
    const float* endT   = (const float*)d_in[5];
    const float* trans  = (const float*)d_in[6];

    float* em   = (float*)d_out;
    float* pred = (float*)d_out + (size_t)BB * TT * KK;

    const size_t SH_BYTES = (size_t)BB * TT * KK * sizeof(float);   // 8 MB
    const size_t HI_BYTES = (size_t)BB * TT * KK;                   // 2 MB
    const size_t WT_OFF   = SH_BYTES + HI_BYTES + 256;              // 64B-aligned
    const size_t NEED = WT_OFF + (size_t)KK * FF * sizeof(float);   // + 256 KB

    if (ws_size >= NEED) {
        float* shist = (float*)d_ws;
        uchar* histg = (uchar*)d_ws + SH_BYTES;
        int*   btarr = (int*)((uchar*)d_ws + SH_BYTES + HI_BYTES);
        float* WT    = (float*)((uchar*)d_ws + WT_OFF);
        wt_kernel<<<256, 256, 0, stream>>>(W, WT);
        emission2_kernel<<<(BB * TT) / 64, 256, 0, stream>>>(X, WT, bias, em);
        viterbi_fwd<<<BB, 64, 0, stream>>>(em, mask, startT, endT, trans, shist, btarr);
        hist_kernel<<<BB * 64, 256, 0, stream>>>(em, mask, trans, shist, histg);
        viterbi_bt<<<BB, 256, 0, stream>>>(histg, btarr, pred);
    } else {
        emission_kernel<<<(BB * TT) / BM, 256, 0, stream>>>(X, W, bias, em);
        viterbi_kernel<<<BB, 256, 0, stream>>>(em, mask, startT, endT, trans, pred);
    }
}

// Round 19
// 218.887 us; speedup vs baseline: 1.9718x; 1.0668x over previous
//
#include <hip/hip_runtime.h>
#include <hip/hip_bf16.h>

#define BB 64
#define TT 512
#define FF 1024
#define KK 64

typedef unsigned char uchar;
typedef float float2v __attribute__((ext_vector_type(2)));

// ---------------- Emission GEMM (round-1 version, measured ~83-88us, 7x) ----------------
#define BM 64
#define BF 64
#define LDA 68

__global__ __launch_bounds__(256)
void emission_kernel(const float* __restrict__ X, const float* __restrict__ W,
                     const float* __restrict__ bias, float* __restrict__ em)
{
    __shared__ float As[BF][LDA];
    __shared__ float Bs[BF][LDA];
    const int tid = threadIdx.x;
    const int row0 = blockIdx.x * BM;
    const int tm = tid & 15;
    const int tn = tid >> 4;
    const int lq = tid & 15;
    const int lr = tid >> 4;

    float acc[4][4];
#pragma unroll
    for (int i = 0; i < 4; ++i)
#pragma unroll
        for (int jj = 0; jj < 4; ++jj) acc[i][jj] = 0.f;

    for (int f0 = 0; f0 < FF; f0 += BF) {
#pragma unroll
        for (int p = 0; p < 4; ++p) {
            const int r = p * 16 + lr;
            float4 a = *(const float4*)(X + (size_t)(row0 + r) * FF + f0 + lq * 4);
            As[lq * 4 + 0][r] = a.x;
            As[lq * 4 + 1][r] = a.y;
            As[lq * 4 + 2][r] = a.z;
            As[lq * 4 + 3][r] = a.w;
            float4 w = *(const float4*)(W + (size_t)r * FF + f0 + lq * 4);
            Bs[lq * 4 + 0][r] = w.x;
            Bs[lq * 4 + 1][r] = w.y;
            Bs[lq * 4 + 2][r] = w.z;
            Bs[lq * 4 + 3][r] = w.w;
        }
        __syncthreads();
#pragma unroll
        for (int f = 0; f < BF; ++f) {
            float4 a = *(const float4*)&As[f][tm * 4];
            float4 b = *(const float4*)&Bs[f][tn * 4];
            acc[0][0] += a.x * b.x; acc[0][1] += a.x * b.y; acc[0][2] += a.x * b.z; acc[0][3] += a.x * b.w;
            acc[1][0] += a.y * b.x; acc[1][1] += a.y * b.y; acc[1][2] += a.y * b.z; acc[1][3] += a.y * b.w;
            acc[2][0] += a.z * b.x; acc[2][1] += a.z * b.y; acc[2][2] += a.z * b.z; acc[2][3] += a.z * b.w;
            acc[3][0] += a.w * b.x; acc[3][1] += a.w * b.y; acc[3][2] += a.w * b.z; acc[3][3] += a.w * b.w;
        }
        __syncthreads();
    }

    const float4 b4 = *(const float4*)(bias + tn * 4);
#pragma unroll
    for (int i = 0; i < 4; ++i) {
        float4 o;
        o.x = acc[i][0] + b4.x;
        o.y = acc[i][1] + b4.y;
        o.z = acc[i][2] + b4.z;
        o.w = acc[i][3] + b4.w;
        *(float4*)(em + (size_t)(row0 + tm * 4 + i) * KK + tn * 4) = o;
    }
}

// ---------------- Forward: value-only, LDS-broadcast + packed adds (r17+r18) ----------------
// r17: LDS uniform-address broadcast beats readlane (620 cy/step). r18: float2
// packed adds (v_pk_add_f32) -> ~375 cy/step, fwd ~80us. tc2 pinned in VGPRs.
#define VSTEP(EV, TIDX) do {                                                   \
    const float2v* sp2 = (const float2v*)&sbuf[(TIDX) & 1][0];                 \
    float m_;                                                                  \
    _Pragma("unroll")                                                          \
    for (int c = 0; c < 8; ++c) {                                              \
        const float2v p0 = sp2[c * 4 + 0] + tc2[c * 4 + 0];                    \
        const float2v p1 = sp2[c * 4 + 1] + tc2[c * 4 + 1];                    \
        const float2v p2 = sp2[c * 4 + 2] + tc2[c * 4 + 2];                    \
        const float2v p3 = sp2[c * 4 + 3] + tc2[c * 4 + 3];                    \
        const float ma = fmaxf(fmaxf(p0.x, p0.y), p1.x);   /* v_max3 */        \
        const float mb = fmaxf(fmaxf(p1.y, p2.x), p2.y);                       \
        const float mc = fmaxf(fmaxf(p3.x, p3.y), ma);                         \
        const float w_ = fmaxf(mb, mc);                                        \
        m_ = (c == 0) ? w_ : fmaxf(m_, w_);                                    \
    }                                                                          \
    score = m_ + (EV);                                                         \
    sbuf[((TIDX) + 1) & 1][j] = score;   /* next step's broadcast, early */    \
    sb[(size_t)(TIDX) * KK + j] = score;                                       \
} while (0)

#define RLANE(I) __uint_as_float((unsigned)__builtin_amdgcn_readlane((int)__float_as_uint(score), (I)))

__global__ __launch_bounds__(64)
__attribute__((amdgpu_waves_per_eu(1, 1)))
void viterbi_fwd(const float* __restrict__ em, const void* __restrict__ maskp,
                 const float* __restrict__ startT, const float* __restrict__ endT,
                 const float* __restrict__ trans, float* __restrict__ shist,
                 int* __restrict__ btarr)
{
    __shared__ float sbuf[2][KK];

    const int b = blockIdx.x;
    const int j = threadIdx.x;

    const uchar* m8 = (const uchar*)maskp;
    const int* m32 = (const int*)maskp;
    const bool u8m = (m8[1] != 0);

    // ---- length precompute (mask monotone: true for t < len) ----
    int myc;
    if (u8m) {
        const uint2 mv = *(const uint2*)(m8 + (size_t)b * TT + j * 8);
        const unsigned s4 = (mv.x & 0x01010101u) + (mv.y & 0x01010101u);
        myc = (int)((s4 * 0x01010101u) >> 24);
    } else {
        const int* mp = m32 + (size_t)b * TT + j * 8;
        const int4 a = *(const int4*)mp;
        const int4 c = *(const int4*)(mp + 4);
        myc = (a.x != 0) + (a.y != 0) + (a.z != 0) + (a.w != 0)
            + (c.x != 0) + (c.y != 0) + (c.z != 0) + (c.w != 0);
    }
#pragma unroll
    for (int o = 1; o < 64; o <<= 1) myc += __shfl_xor(myc, o, 64);
    const int len = myc;

    // trans column as 32 float2 pairs, pinned in VGPRs (r11 regime)
    float2v tc2[32];
#pragma unroll
    for (int i = 0; i < 32; ++i) {
        tc2[i].x = trans[(2 * i) * KK + j];
        tc2[i].y = trans[(2 * i + 1) * KK + j];
    }
#pragma unroll
    for (int i = 0; i < 32; ++i) asm volatile("" : "+v"(tc2[i]));

    const float* emb = em + (size_t)b * TT * KK;
    float* sb = shist + (size_t)b * TT * KK;

    float score = startT[j] + emb[j];   // t = 0
    sb[j] = score;
    sbuf[1][j] = score;                 // t = 1 reads sbuf[1&1]

    float eA = emb[1 * KK + j];
    float eB = emb[2 * KK + j];
    float eC = emb[3 * KK + j];
    float eD = emb[4 * KK + j];

    int t = 1;
    for (; t + 3 < len; t += 4) {
        VSTEP(eA, t);     eA = emb[(size_t)((t + 4 < TT) ? t + 4 : TT - 1) * KK + j];
        VSTEP(eB, t + 1); eB = emb[(size_t)((t + 5 < TT) ? t + 5 : TT - 1) * KK + j];
        VSTEP(eC, t + 2); eC = emb[(size_t)((t + 6 < TT) ? t + 6 : TT - 1) * KK + j];
        VSTEP(eD, t + 3); eD = emb[(size_t)((t + 7 < TT) ? t + 7 : TT - 1) * KK + j];
    }
    for (; t < len; ++t) {
        VSTEP(eA, t);
        eA = eB; eB = eC; eC = eD;
    }

    score += endT[j];
    float bm = -__builtin_inff();
    int bt = 0;
#pragma unroll
    for (int i = 0; i < KK; ++i) {
        const float si = RLANE(i);
        if (si > bm) { bm = si; bt = i; }
    }
    if (j == 0) btarr[b] = bt;
}

// ---------------- hist recompute: massively parallel (validated r8-r18) ----------------
__global__ __launch_bounds__(256)
void hist_kernel(const float* __restrict__ em, const void* __restrict__ maskp,
                 const float* __restrict__ trans, const float* __restrict__ shist,
                 uchar* __restrict__ histg)
{
    const int tid = threadIdx.x;
    const int bid = blockIdx.x;
    const int b = bid >> 6;
    const int t0 = (bid & 63) * 8;

    __shared__ float tl[64][65];
    __shared__ float srow[8][64];

    const uchar* m8 = (const uchar*)maskp;
    const int* m32 = (const int*)maskp;
    const bool u8m = (m8[1] != 0);

#pragma unroll
    for (int p = 0; p < 16; ++p) {
        const int idx = p * 256 + tid;
        tl[idx >> 6][idx & 63] = trans[idx];
    }
#pragma unroll
    for (int p = 0; p < 2; ++p) {
        const int idx = p * 256 + tid;
        const int r = idx >> 6, i2 = idx & 63;
        const int ts = t0 - 1 + r;
        srow[r][i2] = (ts >= 0) ? shist[((size_t)b * TT + ts) * KK + i2] : 0.f;
    }
    __syncthreads();

    const int j = tid & 63;
    const int tq = tid >> 6;

#pragma unroll
    for (int half = 0; half < 2; ++half) {
        const int toff = tq * 2 + half;
        const int t = t0 + toff;
        if (t == 0) continue;
        const int mt = u8m ? (int)m8[b * TT + t] : m32[b * TT + t];
        uchar hv;
        if (!mt) {
            hv = (uchar)j;
        } else {
            const float e = em[((size_t)b * TT + t) * KK + j];
            const float* sr = &srow[toff][0];
            float bm = -__builtin_inff();
            int bi = 0;
#pragma unroll 16
            for (int i = 0; i < KK; ++i) {
                const float cand = (sr[i] + tl[i][j]) + e;   // reference order
                if (cand > bm) { bm = cand; bi = i; }        // strict >: first index
            }
            hv = (uchar)bi;
        }
        histg[((size_t)b * TT + t) * KK + j] = hv;
    }
}

// ---------------- Backtrack (validated r8-r18) ----------------
__global__ __launch_bounds__(256)
void viterbi_bt(const uchar* __restrict__ histg, const int* __restrict__ btarr,
                float* __restrict__ pred)
{
    const int b = blockIdx.x;
    const int tid = threadIdx.x;
    const int w = tid >> 6;
    const int j = tid & 63;

    __shared__ uchar hist[TT][KK];
    __shared__ uchar hypo[8][64][64];

    const uint4* src = (const uint4*)(histg + (size_t)b * TT * KK);
    uint4* dst = (uint4*)&hist[0][0];
#pragma unroll
    for (int p = 0; p < 8; ++p) dst[p * 256 + tid] = src[p * 256 + tid];
    __syncthreads();

    const int bt = btarr[b];

#pragma unroll
    for (int ss = 0; ss < 2; ++ss) {
        const int s = w * 2 + ss;
        int tag = j;
        if (s == 7) {
            hypo[7][63][j] = (uchar)j;
            for (int t = TT - 1; t >= 7 * 64 + 1; --t) {
                tag = hist[t][tag];
                hypo[7][t - 1 - 7 * 64][j] = (uchar)tag;
            }
        } else {
            for (int t = (s + 1) * 64; t >= s * 64 + 1; --t) {
                tag = hist[t][tag];
                hypo[s][t - 1 - s * 64][j] = (uchar)tag;
            }
        }
    }
    __syncthreads();

    int rows_[8];
    rows_[7] = bt;
#pragma unroll
    for (int s = 6; s >= 0; --s) rows_[s] = hypo[s + 1][0][rows_[s + 1]];

    float* pb = pred + (size_t)b * TT;
#pragma unroll
    for (int ss = 0; ss < 2; ++ss) {
        const int s = w * 2 + ss;
        pb[s * 64 + j] = (float)hypo[s][j][rows_[s]];
    }
}

// ---------------- Fallback monolithic viterbi (round-6, proven) ----------------
__global__ __launch_bounds__(256)
void viterbi_kernel(const float* __restrict__ em, const void* __restrict__ maskp,
                    const float* __restrict__ startT, const float* __restrict__ endT,
                    const float* __restrict__ trans, float* __restrict__ pred)
{
    const int b = blockIdx.x;
    const int tid = threadIdx.x;
    const int w = tid >> 6;
    const int j = tid & 63;

    __shared__ uchar hist[TT][KK];
    __shared__ uchar hypo[8][64][64];
    __shared__ int bt_sh;

    const uchar* m8 = (const uchar*)maskp;
    const int* m32 = (const int*)maskp;
    const bool u8m = (m8[1] != 0);

    if (w == 0) {
        float tc[KK];
#pragma unroll
        for (int i = 0; i < KK; ++i) tc[i] = trans[i * KK + j];

        const float* emb = em + (size_t)b * TT * KK;
        float score = startT[j] + emb[j];
        const float endv = endT[j];

        float e_cur = emb[KK + j];
        int   m_cur = u8m ? (int)m8[b * TT + 1] : m32[b * TT + 1];

        int t = 1;
        for (; t < TT; ++t) {
            const int tn2 = (t + 1 < TT) ? (t + 1) : (TT - 1);
            const float e_next = emb[(size_t)tn2 * KK + j];
            const int   m_next = u8m ? (int)m8[b * TT + tn2] : m32[b * TT + tn2];
            if (!m_cur) break;
            float m = -__builtin_inff();
            int idx = 0;
#pragma unroll
            for (int i = 0; i < KK; ++i) {
                const float si = __uint_as_float(__builtin_amdgcn_readlane(__float_as_uint(score), i));
                const float v = (si + tc[i]) + e_cur;
                if (v > m) { m = v; idx = i; }
            }
            score = m;
            hist[t][j] = (uchar)idx;
            e_cur = e_next; m_cur = m_next;
        }
        for (; t < TT; ++t) hist[t][j] = (uchar)j;

        score += endv;
        float bm = -__builtin_inff();
        int bt = 0;
#pragma unroll
        for (int i = 0; i < KK; ++i) {
            const float si = __uint_as_float(__builtin_amdgcn_readlane(__float_as_uint(score), i));
            if (si > bm) { bm = si; bt = i; }
        }
        if (j == 0) bt_sh = bt;
    }
    __syncthreads();

#pragma unroll
    for (int ss = 0; ss < 2; ++ss) {
        const int s = w * 2 + ss;
        int tag = j;
        if (s == 7) {
            hypo[7][63][j] = (uchar)j;
            for (int t = TT - 1; t >= 7 * 64 + 1; --t) {
                tag = hist[t][tag];
                hypo[7][t - 1 - 7 * 64][j] = (uchar)tag;
            }
        } else {
            for (int t = (s + 1) * 64; t >= s * 64 + 1; --t) {
                tag = hist[t][tag];
                hypo[s][t - 1 - s * 64][j] = (uchar)tag;
            }
        }
    }
    __syncthreads();

    const int bt = bt_sh;
    int rows_[8];
    rows_[7] = bt;
#pragma unroll
    for (int s = 6; s >= 0; --s) rows_[s] = hypo[s + 1][0][rows_[s + 1]];

    float* pb = pred + (size_t)b * TT;
#pragma unroll
    for (int ss = 0; ss < 2; ++ss) {
        const int s = w * 2 + ss;
        pb[s * 64 + j] = (float)hypo[s][j][rows_[s]];
    }
}

extern "C" void kernel_launch(void* const* d_in, const int* in_sizes, int n_in,
                              void* d_out, int out_size, void* d_ws, size_t ws_size,
                              hipStream_t stream) {
    const float* X      = (const float*)d_in[0];
    const void*  mask   = d_in[1];
    const float* W      = (const float*)d_in[2];
    const float* bias   = (const float*)d_in[3];
    const float* startT = (const float*)d_in[4];
    const float* endT   = (const float*)d_in[5];
    const float* trans  = (const float*)d_in[6];

    float* em   = (float*)d_out;
    float* pred = (float*)d_out + (size_t)BB * TT * KK;

    emission_kernel<<<(BB * TT) / BM, 256, 0, stream>>>(X, W, bias, em);

    const size_t SH_BYTES = (size_t)BB * TT * KK * sizeof(float);   // 8 MB
    const size_t HI_BYTES = (size_t)BB * TT * KK;                   // 2 MB
    const size_t NEED = SH_BYTES + HI_BYTES + 256;

    if (ws_size >= NEED) {
        float* shist = (float*)d_ws;
        uchar* histg = (uchar*)d_ws + SH_BYTES;
        int*   btarr = (int*)((uchar*)d_ws + SH_BYTES + HI_BYTES);
        viterbi_fwd<<<BB, 64, 0, stream>>>(em, mask, startT, endT, trans, shist, btarr);
        hist_kernel<<<BB * 64, 256, 0, stream>>>(em, mask, trans, shist, histg);
        viterbi_bt<<<BB, 256, 0, stream>>>(histg, btarr, pred);
    } else {
        viterbi_kernel<<<BB, 256, 0, stream>>>(em, mask, startT, endT, trans, pred);
    }
}

// Round 20
// 200.095 us; speedup vs baseline: 2.1570x; 1.0939x over previous
//
#include <hip/hip_runtime.h>
#include <hip/hip_bf16.h>

#define BB 64
#define TT 512
#define FF 1024
#define KK 64
#define EMSZ ((size_t)BB * TT * KK)

typedef unsigned char uchar;
typedef float float2v __attribute__((ext_vector_type(2)));

// ---------------- Emission v3: 8x8 microtile, f-split x4 ----------------
// r1 kernel is LDS-pipe-bound (2 b128 per 16 FMA -> 196k cy/CU = 82us).
// 8x8 microtile: 4 b128 per 64 FMA -> 98k cy/CU ~= 41us. 256 threads,
// tile 256 rows x 64 cols x 256 f; 512 blocks (~2/CU -> 2 waves/SIMD).
#define E3T 32     // f per subtile
#define E3PA 260   // A row stride (floats): 1040B rows, 16B-aligned, 2-way banks
#define E3PB 68

__global__ __launch_bounds__(256)
void emission3_kernel(const float* __restrict__ X, const float* __restrict__ W,
                      float* __restrict__ part)
{
    __shared__ float As[E3T][E3PA];   // As[f][row]
    __shared__ float Bs[E3T][E3PB];   // Bs[f][col]
    const int tid = threadIdx.x;
    const int bid = blockIdx.x;
    const int fs = bid & 3;           // f-split 0..3
    const int rb = bid >> 2;          // row block 0..127
    const int row0 = rb * 256;
    const int fb = fs * 256;
    const int rg = tid >> 3;          // 0..31 (wave covers rg 0..7 => 2-way banks)
    const int cg = tid & 7;           // 0..7
    const int r_base = rg * 8;
    const int c_base = cg * 8;

    float acc[8][8];
#pragma unroll
    for (int i = 0; i < 8; ++i)
#pragma unroll
        for (int j = 0; j < 8; ++j) acc[i][j] = 0.f;

    for (int ft = 0; ft < 256; ft += E3T) {
        // stage A: 256 rows x 32 f = 2048 float4
#pragma unroll
        for (int p = 0; p < 8; ++p) {
            const int idx = p * 256 + tid;
            const int row = idx >> 3;
            const int fq = idx & 7;
            const float4 a = *(const float4*)(X + (size_t)(row0 + row) * FF + fb + ft + fq * 4);
            As[fq * 4 + 0][row] = a.x;
            As[fq * 4 + 1][row] = a.y;
            As[fq * 4 + 2][row] = a.z;
            As[fq * 4 + 3][row] = a.w;
        }
        // stage B: 64 cols x 32 f = 512 float4
#pragma unroll
        for (int p = 0; p < 2; ++p) {
            const int idx = p * 256 + tid;
            const int c = idx >> 3;
            const int fq = idx & 7;
            const float4 w = *(const float4*)(W + (size_t)c * FF + fb + ft + fq * 4);
            Bs[fq * 4 + 0][c] = w.x;
            Bs[fq * 4 + 1][c] = w.y;
            Bs[fq * 4 + 2][c] = w.z;
            Bs[fq * 4 + 3][c] = w.w;
        }
        __syncthreads();
#pragma unroll
        for (int f = 0; f < E3T; ++f) {
            const float4 a0 = *(const float4*)&As[f][r_base];
            const float4 a1 = *(const float4*)&As[f][r_base + 4];
            const float4 b0 = *(const float4*)&Bs[f][c_base];
            const float4 b1 = *(const float4*)&Bs[f][c_base + 4];
            const float av[8] = { a0.x, a0.y, a0.z, a0.w, a1.x, a1.y, a1.z, a1.w };
            const float bv[8] = { b0.x, b0.y, b0.z, b0.w, b1.x, b1.y, b1.z, b1.w };
#pragma unroll
            for (int i = 0; i < 8; ++i)
#pragma unroll
                for (int j = 0; j < 8; ++j)
                    acc[i][j] = fmaf(av[i], bv[j], acc[i][j]);
        }
        __syncthreads();
    }

    float* pp = part + (size_t)fs * EMSZ;
#pragma unroll
    for (int i = 0; i < 8; ++i) {
        float4 o0, o1;
        o0.x = acc[i][0]; o0.y = acc[i][1]; o0.z = acc[i][2]; o0.w = acc[i][3];
        o1.x = acc[i][4]; o1.y = acc[i][5]; o1.z = acc[i][6]; o1.w = acc[i][7];
        float* op = pp + (size_t)(row0 + r_base + i) * KK + c_base;
        *(float4*)(op + 0) = o0;
        *(float4*)(op + 4) = o1;
    }
}

// combine partials + bias (fixed order -> deterministic)
__global__ __launch_bounds__(256)
void emadd_kernel(const float* __restrict__ part, const float* __restrict__ bias,
                  float* __restrict__ em)
{
    const size_t i = (size_t)blockIdx.x * 256 + threadIdx.x;   // f4 index
    const float4* p0 = (const float4*)part;
    const float4* p1 = (const float4*)(part + EMSZ);
    const float4* p2 = (const float4*)(part + 2 * EMSZ);
    const float4* p3 = (const float4*)(part + 3 * EMSZ);
    const float4 a = p0[i], b = p1[i], c = p2[i], d = p3[i];
    const float4 bv = *(const float4*)(bias + ((int)(i & 15)) * 4);
    float4 o;
    o.x = (((a.x + b.x) + c.x) + d.x) + bv.x;
    o.y = (((a.y + b.y) + c.y) + d.y) + bv.y;
    o.z = (((a.z + b.z) + c.z) + d.z) + bv.z;
    o.w = (((a.w + b.w) + c.w) + d.w) + bv.w;
    ((float4*)em)[i] = o;
}

// ---------------- Emission v1 (fallback, measured ~84us 7x) ----------------
#define BM 64
#define BF 64
#define LDA 68

__global__ __launch_bounds__(256)
void emission_kernel(const float* __restrict__ X, const float* __restrict__ W,
                     const float* __restrict__ bias, float* __restrict__ em)
{
    __shared__ float As[BF][LDA];
    __shared__ float Bs[BF][LDA];
    const int tid = threadIdx.x;
    const int row0 = blockIdx.x * BM;
    const int tm = tid & 15;
    const int tn = tid >> 4;
    const int lq = tid & 15;
    const int lr = tid >> 4;

    float acc[4][4];
#pragma unroll
    for (int i = 0; i < 4; ++i)
#pragma unroll
        for (int jj = 0; jj < 4; ++jj) acc[i][jj] = 0.f;

    for (int f0 = 0; f0 < FF; f0 += BF) {
#pragma unroll
        for (int p = 0; p < 4; ++p) {
            const int r = p * 16 + lr;
            float4 a = *(const float4*)(X + (size_t)(row0 + r) * FF + f0 + lq * 4);
            As[lq * 4 + 0][r] = a.x;
            As[lq * 4 + 1][r] = a.y;
            As[lq * 4 + 2][r] = a.z;
            As[lq * 4 + 3][r] = a.w;
            float4 w = *(const float4*)(W + (size_t)r * FF + f0 + lq * 4);
            Bs[lq * 4 + 0][r] = w.x;
            Bs[lq * 4 + 1][r] = w.y;
            Bs[lq * 4 + 2][r] = w.z;
            Bs[lq * 4 + 3][r] = w.w;
        }
        __syncthreads();
#pragma unroll
        for (int f = 0; f < BF; ++f) {
            float4 a = *(const float4*)&As[f][tm * 4];
            float4 b = *(const float4*)&Bs[f][tn * 4];
            acc[0][0] += a.x * b.x; acc[0][1] += a.x * b.y; acc[0][2] += a.x * b.z; acc[0][3] += a.x * b.w;
            acc[1][0] += a.y * b.x; acc[1][1] += a.y * b.y; acc[1][2] += a.y * b.z; acc[1][3] += a.y * b.w;
            acc[2][0] += a.z * b.x; acc[2][1] += a.z * b.y; acc[2][2] += a.z * b.z; acc[2][3] += a.z * b.w;
            acc[3][0] += a.w * b.x; acc[3][1] += a.w * b.y; acc[3][2] += a.w * b.z; acc[3][3] += a.w * b.w;
        }
        __syncthreads();
    }

    const float4 b4 = *(const float4*)(bias + tn * 4);
#pragma unroll
    for (int i = 0; i < 4; ++i) {
        float4 o;
        o.x = acc[i][0] + b4.x;
        o.y = acc[i][1] + b4.y;
        o.z = acc[i][2] + b4.z;
        o.w = acc[i][3] + b4.w;
        *(float4*)(em + (size_t)(row0 + tm * 4 + i) * KK + tn * 4) = o;
    }
}

// ---------------- Forward: value-only, LDS-broadcast + packed adds (r17-r19) ----------------
#define VSTEP(EV, TIDX) do {                                                   \
    const float2v* sp2 = (const float2v*)&sbuf[(TIDX) & 1][0];                 \
    float m_;                                                                  \
    _Pragma("unroll")                                                          \
    for (int c = 0; c < 8; ++c) {                                              \
        const float2v p0 = sp2[c * 4 + 0] + tc2[c * 4 + 0];                    \
        const float2v p1 = sp2[c * 4 + 1] + tc2[c * 4 + 1];                    \
        const float2v p2 = sp2[c * 4 + 2] + tc2[c * 4 + 2];                    \
        const float2v p3 = sp2[c * 4 + 3] + tc2[c * 4 + 3];                    \
        const float ma = fmaxf(fmaxf(p0.x, p0.y), p1.x);   /* v_max3 */        \
        const float mb = fmaxf(fmaxf(p1.y, p2.x), p2.y);                       \
        const float mc = fmaxf(fmaxf(p3.x, p3.y), ma);                         \
        const float w_ = fmaxf(mb, mc);                                        \
        m_ = (c == 0) ? w_ : fmaxf(m_, w_);                                    \
    }                                                                          \
    score = m_ + (EV);                                                         \
    sbuf[((TIDX) + 1) & 1][j] = score;                                         \
    sb[(size_t)(TIDX) * KK + j] = score;                                       \
} while (0)

#define RLANE(I) __uint_as_float((unsigned)__builtin_amdgcn_readlane((int)__float_as_uint(score), (I)))

__global__ __launch_bounds__(64)
__attribute__((amdgpu_waves_per_eu(1, 1)))
void viterbi_fwd(const float* __restrict__ em, const void* __restrict__ maskp,
                 const float* __restrict__ startT, const float* __restrict__ endT,
                 const float* __restrict__ trans, float* __restrict__ shist,
                 int* __restrict__ btarr)
{
    __shared__ float sbuf[2][KK];

    const int b = blockIdx.x;
    const int j = threadIdx.x;

    const uchar* m8 = (const uchar*)maskp;
    const int* m32 = (const int*)maskp;
    const bool u8m = (m8[1] != 0);

    int myc;
    if (u8m) {
        const uint2 mv = *(const uint2*)(m8 + (size_t)b * TT + j * 8);
        const unsigned s4 = (mv.x & 0x01010101u) + (mv.y & 0x01010101u);
        myc = (int)((s4 * 0x01010101u) >> 24);
    } else {
        const int* mp = m32 + (size_t)b * TT + j * 8;
        const int4 a = *(const int4*)mp;
        const int4 c = *(const int4*)(mp + 4);
        myc = (a.x != 0) + (a.y != 0) + (a.z != 0) + (a.w != 0)
            + (c.x != 0) + (c.y != 0) + (c.z != 0) + (c.w != 0);
    }
#pragma unroll
    for (int o = 1; o < 64; o <<= 1) myc += __shfl_xor(myc, o, 64);
    const int len = myc;

    float2v tc2[32];
#pragma unroll
    for (int i = 0; i < 32; ++i) {
        tc2[i].x = trans[(2 * i) * KK + j];
        tc2[i].y = trans[(2 * i + 1) * KK + j];
    }
#pragma unroll
    for (int i = 0; i < 32; ++i) asm volatile("" : "+v"(tc2[i]));

    const float* emb = em + (size_t)b * TT * KK;
    float* sb = shist + (size_t)b * TT * KK;

    float score = startT[j] + emb[j];
    sb[j] = score;
    sbuf[1][j] = score;

    float eA = emb[1 * KK + j];
    float eB = emb[2 * KK + j];
    float eC = emb[3 * KK + j];
    float eD = emb[4 * KK + j];

    int t = 1;
    for (; t + 3 < len; t += 4) {
        VSTEP(eA, t);     eA = emb[(size_t)((t + 4 < TT) ? t + 4 : TT - 1) * KK + j];
        VSTEP(eB, t + 1); eB = emb[(size_t)((t + 5 < TT) ? t + 5 : TT - 1) * KK + j];
        VSTEP(eC, t + 2); eC = emb[(size_t)((t + 6 < TT) ? t + 6 : TT - 1) * KK + j];
        VSTEP(eD, t + 3); eD = emb[(size_t)((t + 7 < TT) ? t + 7 : TT - 1) * KK + j];
    }
    for (; t < len; ++t) {
        VSTEP(eA, t);
        eA = eB; eB = eC; eC = eD;
    }

    score += endT[j];
    float bm = -__builtin_inff();
    int bt = 0;
#pragma unroll
    for (int i = 0; i < KK; ++i) {
        const float si = RLANE(i);
        if (si > bm) { bm = si; bt = i; }
    }
    if (j == 0) btarr[b] = bt;
}

// ---------------- hist recompute (validated r8-r19) ----------------
__global__ __launch_bounds__(256)
void hist_kernel(const float* __restrict__ em, const void* __restrict__ maskp,
                 const float* __restrict__ trans, const float* __restrict__ shist,
                 uchar* __restrict__ histg)
{
    const int tid = threadIdx.x;
    const int bid = blockIdx.x;
    const int b = bid >> 6;
    const int t0 = (bid & 63) * 8;

    __shared__ float tl[64][65];
    __shared__ float srow[8][64];

    const uchar* m8 = (const uchar*)maskp;
    const int* m32 = (const int*)maskp;
    const bool u8m = (m8[1] != 0);

#pragma unroll
    for (int p = 0; p < 16; ++p) {
        const int idx = p * 256 + tid;
        tl[idx >> 6][idx & 63] = trans[idx];
    }
#pragma unroll
    for (int p = 0; p < 2; ++p) {
        const int idx = p * 256 + tid;
        const int r = idx >> 6, i2 = idx & 63;
        const int ts = t0 - 1 + r;
        srow[r][i2] = (ts >= 0) ? shist[((size_t)b * TT + ts) * KK + i2] : 0.f;
    }
    __syncthreads();

    const int j = tid & 63;
    const int tq = tid >> 6;

#pragma unroll
    for (int half = 0; half < 2; ++half) {
        const int toff = tq * 2 + half;
        const int t = t0 + toff;
        if (t == 0) continue;
        const int mt = u8m ? (int)m8[b * TT + t] : m32[b * TT + t];
        uchar hv;
        if (!mt) {
            hv = (uchar)j;
        } else {
            const float e = em[((size_t)b * TT + t) * KK + j];
            const float* sr = &srow[toff][0];
            float bm = -__builtin_inff();
            int bi = 0;
#pragma unroll 16
            for (int i = 0; i < KK; ++i) {
                const float cand = (sr[i] + tl[i][j]) + e;   // reference order
                if (cand > bm) { bm = cand; bi = i; }        // strict >: first index
            }
            hv = (uchar)bi;
        }
        histg[((size_t)b * TT + t) * KK + j] = hv;
    }
}

// ---------------- Backtrack (validated r8-r19) ----------------
__global__ __launch_bounds__(256)
void viterbi_bt(const uchar* __restrict__ histg, const int* __restrict__ btarr,
                float* __restrict__ pred)
{
    const int b = blockIdx.x;
    const int tid = threadIdx.x;
    const int w = tid >> 6;
    const int j = tid & 63;

    __shared__ uchar hist[TT][KK];
    __shared__ uchar hypo[8][64][64];

    const uint4* src = (const uint4*)(histg + (size_t)b * TT * KK);
    uint4* dst = (uint4*)&hist[0][0];
#pragma unroll
    for (int p = 0; p < 8; ++p) dst[p * 256 + tid] = src[p * 256 + tid];
    __syncthreads();

    const int bt = btarr[b];

#pragma unroll
    for (int ss = 0; ss < 2; ++ss) {
        const int s = w * 2 + ss;
        int tag = j;
        if (s == 7) {
            hypo[7][63][j] = (uchar)j;
            for (int t = TT - 1; t >= 7 * 64 + 1; --t) {
                tag = hist[t][tag];
                hypo[7][t - 1 - 7 * 64][j] = (uchar)tag;
            }
        } else {
            for (int t = (s + 1) * 64; t >= s * 64 + 1; --t) {
                tag = hist[t][tag];
                hypo[s][t - 1 - s * 64][j] = (uchar)tag;
            }
        }
    }
    __syncthreads();

    int rows_[8];
    rows_[7] = bt;
#pragma unroll
    for (int s = 6; s >= 0; --s) rows_[s] = hypo[s + 1][0][rows_[s + 1]];

    float* pb = pred + (size_t)b * TT;
#pragma unroll
    for (int ss = 0; ss < 2; ++ss) {
        const int s = w * 2 + ss;
        pb[s * 64 + j] = (float)hypo[s][j][rows_[s]];
    }
}

// ---------------- Fallback monolithic viterbi (round-6, proven) ----------------
__global__ __launch_bounds__(256)
void viterbi_kernel(const float* __restrict__ em, const void* __restrict__ maskp,
                    const float* __restrict__ startT, const float* __restrict__ endT,
                    const float* __restrict__ trans, float* __restrict__ pred)
{
    const int b = blockIdx.x;
    const int tid = threadIdx.x;
    const int w = tid >> 6;
    const int j = tid & 63;

    __shared__ uchar hist[TT][KK];
    __shared__ uchar hypo[8][64][64];
    __shared__ int bt_sh;

    const uchar* m8 = (const uchar*)maskp;
    const int* m32 = (const int*)maskp;
    const bool u8m = (m8[1] != 0);

    if (w == 0) {
        float tc[KK];
#pragma unroll
        for (int i = 0; i < KK; ++i) tc[i] = trans[i * KK + j];

        const float* emb = em + (size_t)b * TT * KK;
        float score = startT[j] + emb[j];
        const float endv = endT[j];

        float e_cur = emb[KK + j];
        int   m_cur = u8m ? (int)m8[b * TT + 1] : m32[b * TT + 1];

        int t = 1;
        for (; t < TT; ++t) {
            const int tn2 = (t + 1 < TT) ? (t + 1) : (TT - 1);
            const float e_next = emb[(size_t)tn2 * KK + j];
            const int   m_next = u8m ? (int)m8[b * TT + tn2] : m32[b * TT + tn2];
            if (!m_cur) break;
            float m = -__builtin_inff();
            int idx = 0;
#pragma unroll
            for (int i = 0; i < KK; ++i) {
                const float si = __uint_as_float(__builtin_amdgcn_readlane(__float_as_uint(score), i));
                const float v = (si + tc[i]) + e_cur;
                if (v > m) { m = v; idx = i; }
            }
            score = m;
            hist[t][j] = (uchar)idx;
            e_cur = e_next; m_cur = m_next;
        }
        for (; t < TT; ++t) hist[t][j] = (uchar)j;

        score += endv;
        float bm = -__builtin_inff();
        int bt = 0;
#pragma unroll
        for (int i = 0; i < KK; ++i) {
            const float si = __uint_as_float(__builtin_amdgcn_readlane(__float_as_uint(score), i));
            if (si > bm) { bm = si; bt = i; }
        }
        if (j == 0) bt_sh = bt;
    }
    __syncthreads();

#pragma unroll
    for (int ss = 0; ss < 2; ++ss) {
        const int s = w * 2 + ss;
        int tag = j;
        if (s == 7) {
            hypo[7][63][j] = (uchar)j;
            for (int t = TT - 1; t >= 7 * 64 + 1; --t) {
                tag = hist[t][tag];
                hypo[7][t - 1 - 7 * 64][j] = (uchar)tag;
            }
        } else {
            for (int t = (s + 1) * 64; t >= s * 64 + 1; --t) {
                tag = hist[t][tag];
                hypo[s][t - 1 - s * 64][j] = (uchar)tag;
            }
        }
    }
    __syncthreads();

    const int bt = bt_sh;
    int rows_[8];
    rows_[7] = bt;
#pragma unroll
    for (int s = 6; s >= 0; --s) rows_[s] = hypo[s + 1][0][rows_[s + 1]];

    float* pb = pred + (size_t)b * TT;
#pragma unroll
    for (int ss = 0; ss < 2; ++ss) {
        const int s = w * 2 + ss;
        pb[s * 64 + j] = (float)hypo[s][j][rows_[s]];
    }
}

extern "C" void kernel_launch(void* const* d_in, const int* in_sizes, int n_in,
                              void* d_out, int out_size, void* d_ws, size_t ws_size,
                              hipStream_t stream) {
    const float* X      = (const float*)d_in[0];
    const void*  mask   = d_in[1];
    const float* W      = (const float*)d_in[2];
    const float* bias   = (const float*)d_in[3];
    const float* startT = (const float*)d_in[4];
    const float* endT   = (const float*)d_in[5];
    const float* trans  = (const float*)d_in[6];

    float* em   = (float*)d_out;
    float* pred = (float*)d_out + EMSZ;

    const size_t SH_BYTES = EMSZ * sizeof(float);          // 8 MB
    const size_t HI_BYTES = EMSZ;                          // 2 MB
    const size_t NEED  = SH_BYTES + HI_BYTES + 256;        // split viterbi path
    const size_t P_OFF = NEED;                             // partials (16B-aligned)
    const size_t NEED3 = P_OFF + 4 * EMSZ * sizeof(float); // + 32 MB

    if (ws_size >= NEED) {
        float* shist = (float*)d_ws;
        uchar* histg = (uchar*)d_ws + SH_BYTES;
        int*   btarr = (int*)((uchar*)d_ws + SH_BYTES + HI_BYTES);

        if (ws_size >= NEED3) {
            float* part = (float*)((uchar*)d_ws + P_OFF);
            emission3_kernel<<<512, 256, 0, stream>>>(X, W, part);
            emadd_kernel<<<(int)(EMSZ / 4 / 256), 256, 0, stream>>>(part, bias, em);
        } else {
            emission_kernel<<<(BB * TT) / BM, 256, 0, stream>>>(X, W, bias, em);
        }
        viterbi_fwd<<<BB, 64, 0, stream>>>(em, mask, startT, endT, trans, shist, btarr);
        hist_kernel<<<BB * 64, 256, 0, stream>>>(em, mask, trans, shist, histg);
        viterbi_bt<<<BB, 256, 0, stream>>>(histg, btarr, pred);
    } else {
        emission_kernel<<<(BB * TT) / BM, 256, 0, stream>>>(X, W, bias, em);
        viterbi_kernel<<<BB, 256, 0, stream>>>(em, mask, startT, endT, trans, pred);
    }
}